// Round 5
// baseline (473.291 us; speedup 1.0000x reference)
//
#include <hip/hip_runtime.h>
#include <hip/hip_bf16.h>
#include <math.h>

typedef __bf16 bf16;
typedef __bf16 bf16x8 __attribute__((ext_vector_type(8)));
typedef float f32x4 __attribute__((ext_vector_type(4)));

// ---------------------------------------------------------------------------
// helpers
// ---------------------------------------------------------------------------
__device__ __forceinline__ void gload_lds16(const bf16* g, bf16* l) {
    __builtin_amdgcn_global_load_lds(
        (const __attribute__((address_space(1))) void*)g,
        (__attribute__((address_space(3))) void*)l,
        16, 0, 0);
}

// XOR swizzle for [R][64] bf16 tiles (attention K/V/P).
__device__ __forceinline__ int swz_idx(int row, int col) {
    return ((row) << 6) + (((((col) >> 3) ^ ((row) & 7)) << 3) | ((col) & 7));
}
#define LDS_SWZ8(row, c8) ((((row)) << 6) + ((((c8) ^ ((row) & 7))) << 3))

template <int ROWS>
__device__ __forceinline__ void stage_swz(const bf16* __restrict__ src, long rstride,
                                          bf16* lds, int tid) {
#pragma unroll
    for (int pass = 0; pass < ROWS / 32; ++pass) {
        int e = pass * 2048 + tid * 8;
        int r = e >> 6;
        int c8 = (e >> 3) & 7;
        int sc8 = c8 ^ (r & 7);
        gload_lds16(src + (long)r * rstride + sc8 * 8, lds + e);
    }
}

// ---------------------------------------------------------------------------
// Weight transpose + fp32->bf16:  src [R][C] fp32  ->  dst [C][R] bf16
// ---------------------------------------------------------------------------
__global__ void transpose_cvt(const float* __restrict__ src, bf16* __restrict__ dst,
                              int R, int C) {
    __shared__ float tile[32][33];
    int bx = blockIdx.x * 32;
    int by = blockIdx.y * 32;
    int tx = threadIdx.x, ty = threadIdx.y;
#pragma unroll
    for (int j = 0; j < 32; j += 8)
        tile[ty + j][tx] = src[(long)(by + ty + j) * C + bx + tx];
    __syncthreads();
#pragma unroll
    for (int j = 0; j < 32; j += 8)
        dst[(long)(bx + ty + j) * R + by + tx] = (bf16)tile[tx][ty + j];
}

__global__ void cvt_bf16_kernel(const float* __restrict__ src, bf16* __restrict__ dst,
                                long n) {
    long i = ((long)blockIdx.x * blockDim.x + threadIdx.x) * 4;
    if (i < n) {
        float4 v = *(const float4*)(src + i);
        short4 pk;
        pk.x = (short)__builtin_bit_cast(unsigned short, (bf16)v.x);
        pk.y = (short)__builtin_bit_cast(unsigned short, (bf16)v.y);
        pk.z = (short)__builtin_bit_cast(unsigned short, (bf16)v.z);
        pk.w = (short)__builtin_bit_cast(unsigned short, (bf16)v.w);
        *(short4*)(dst + i) = pk;
    }
}

// ---------------------------------------------------------------------------
// Triple-buffered deep-pipeline GEMM: C[M][N] = A[M][K]*Bt[N][K]^T + bias.
// BM=256 BN=128 BK=64, 512 thr (8 waves 4Mx2N, 64x64 out/wave).
// Per K-tile: {issue 6 gload_lds for tile t+2 -> 16 ds_read + 32 MFMA
// (compiler-scheduled) -> s_waitcnt vmcnt(6); s_barrier}.
// vmcnt(6) leaves tile t+2's loads in flight; waits only tile t+1's, which
// were issued TWO tiles earlier (slack >> HBM latency). Never vmcnt(0) in
// the main loop (T4). LDS 144 KiB (3 bufs), 1 block/CU.
// MODE 0: qkv split epilogue; 1: fp32 out; 2: GELU->bf16; 3: fp32 out.
// ---------------------------------------------------------------------------
template <int MODE, int KT>
__global__ __launch_bounds__(512, 2)
void gemm_tb(const bf16* __restrict__ A, const bf16* __restrict__ Bt,
             const float* __restrict__ bias,
             float* __restrict__ Cf, bf16* __restrict__ Cb0,
             bf16* __restrict__ Cb1, bf16* __restrict__ Cb2,
             int M, int N) {
    __shared__ __align__(16) bf16 lsA[3][2][256 * 32];   // 96 KiB  [buf][kk]
    __shared__ __align__(16) bf16 lsB[3][2][128 * 32];   // 48 KiB

    constexpr int NT = KT / 64;

    // XCD-aware bijective swizzle of flattened block idx (grid % 8 == 0)
    const int nwg = gridDim.x * gridDim.y;
    const int lin = blockIdx.y * gridDim.x + blockIdx.x;
    const int swz = (lin & 7) * (nwg >> 3) + (lin >> 3);
    const int bx = swz % gridDim.x, by = swz / gridDim.x;
    const int brow = by * 256, bcol = bx * 128;

    const int tid = threadIdx.x;
    const int lane = tid & 63;
    const int wid = tid >> 6;
    const int wm = wid >> 1, wn = wid & 1;
    const int l15 = lane & 15, l4 = lane >> 4;

    f32x4 acc[4][4] = {};

    // ---- precomputed LDS read bases (bytes); kk/frag become imm ----
    const int xorkey = (l4 ^ ((l15 >> 1) & 3)) << 3;
    const int abyte = ((wm * 64 + l15) * 32 + xorkey) * 2;
    const int bbyte = ((wn * 64 + l15) * 32 + xorkey) * 2;

    // ---- persistent global staging pointers ----
    const int tid4 = tid >> 2;
    const int cs8 = (((tid & 3) ^ ((tid >> 3) & 3))) * 8;
    const bf16* gA0 = A + (long)(brow + tid4) * KT + cs8;
    const bf16* gA1 = gA0 + (long)128 * KT;
    const bf16* gB0 = Bt + (long)(bcol + tid4) * KT + cs8;
    const int tid8 = tid * 8;

    // rotating buffer pointers (explicit rotation, no runtime-indexed array)
    bf16* pa0 = &lsA[0][0][0]; bf16* pa1 = &lsA[1][0][0]; bf16* pa2 = &lsA[2][0][0];
    bf16* pb0 = &lsB[0][0][0]; bf16* pb1 = &lsB[1][0][0]; bf16* pb2 = &lsB[2][0][0];

#define STAGE(pa, pb)                                                             \
    do {                                                                          \
        gload_lds16(gA0,      (pa) + tid8);                                       \
        gload_lds16(gA1,      (pa) + tid8 + 4096);                                \
        gload_lds16(gB0,      (pb) + tid8);                                       \
        gload_lds16(gA0 + 32, (pa) + 8192 + tid8);                                \
        gload_lds16(gA1 + 32, (pa) + 8192 + tid8 + 4096);                         \
        gload_lds16(gB0 + 32, (pb) + 4096 + tid8);                                \
        gA0 += 64; gA1 += 64; gB0 += 64;                                          \
    } while (0)

#define COMPUTE(pa, pb)                                                           \
    do {                                                                          \
        const char* pac = (const char*)(pa);                                      \
        const char* pbc = (const char*)(pb);                                      \
        _Pragma("unroll")                                                         \
        for (int kk = 0; kk < 2; ++kk) {                                          \
            bf16x8 aF[4], bF[4];                                                  \
            _Pragma("unroll")                                                     \
            for (int m = 0; m < 4; ++m)                                           \
                aF[m] = *(const bf16x8*)(pac + (kk * 16384 + m * 1024) + abyte);  \
            _Pragma("unroll")                                                     \
            for (int n = 0; n < 4; ++n)                                           \
                bF[n] = *(const bf16x8*)(pbc + (kk * 8192 + n * 1024) + bbyte);   \
            __builtin_amdgcn_s_setprio(1);                                        \
            _Pragma("unroll")                                                     \
            for (int m = 0; m < 4; ++m)                                           \
                _Pragma("unroll")                                                 \
                for (int n = 0; n < 4; ++n)                                       \
                    acc[m][n] = __builtin_amdgcn_mfma_f32_16x16x32_bf16(          \
                        aF[m], bF[n], acc[m][n], 0, 0, 0);                        \
            __builtin_amdgcn_s_setprio(0);                                        \
        }                                                                         \
    } while (0)

    // ---- prologue: stage tiles 0 and 1; wait tile 0 (6 newest may fly) ----
    STAGE(pa0, pb0);
    STAGE(pa1, pb1);
    asm volatile("s_waitcnt vmcnt(6)\n\ts_barrier" ::: "memory");

#pragma unroll 1
    for (int t = 0; t < NT; ++t) {
        if (t + 2 < NT) STAGE(pa2, pb2);
        COMPUTE(pa0, pb0);
        if (t + 2 < NT) {
            asm volatile("s_waitcnt vmcnt(6)\n\ts_barrier" ::: "memory");
        } else if (t + 1 < NT) {
            asm volatile("s_waitcnt vmcnt(0)\n\ts_barrier" ::: "memory");
        }
        bf16* ta = pa0; pa0 = pa1; pa1 = pa2; pa2 = ta;
        bf16* tb = pb0; pb0 = pb1; pb1 = pb2; pb2 = tb;
    }

#undef STAGE
#undef COMPUTE

    // ---- epilogue ----
#pragma unroll
    for (int m = 0; m < 4; ++m) {
#pragma unroll
        for (int n = 0; n < 4; ++n) {
            int colb = bcol + wn * 64 + n * 16 + l15;
            float bv = bias[colb];
#pragma unroll
            for (int i = 0; i < 4; ++i) {
                int row = brow + wm * 64 + m * 16 + l4 * 4 + i;
                int col = colb;
                float v = acc[m][n][i] + bv;
                if (MODE == 0) {
                    int b = row >> 10, nn = row & 1023;
                    int s = col >> 10, rem = col & 1023;
                    int h = rem >> 6, d = rem & 63;
                    long bh = (long)b * 16 + h;
                    if (s == 0)      Cb0[(bh * 1024 + nn) * 64 + d] = (bf16)(v * 0.125f);
                    else if (s == 1) Cb1[(bh * 1024 + nn) * 64 + d] = (bf16)v;
                    else             Cb2[(bh * 64 + d) * 1024 + nn] = (bf16)v;
                } else if (MODE == 1) {
                    Cf[(long)row * N + col] = v;
                } else if (MODE == 2) {
                    float g = 0.5f * v * (1.0f + erff(v * 0.70710678118f));
                    Cb0[(long)row * N + col] = (bf16)g;
                } else {
                    Cf[(long)row * N + col] = v;
                }
            }
        }
    }
}

// ---------------------------------------------------------------------------
// Flash attention, no-max softmax (bounded S), dbuf K/V via global_load_lds.
// ---------------------------------------------------------------------------
__global__ __launch_bounds__(256, 2)
void attn_flash(const bf16* __restrict__ Q, const bf16* __restrict__ Kv,
                const bf16* __restrict__ Vt, bf16* __restrict__ Y) {
    __shared__ __align__(16) bf16 lsK[2][64 * 64];
    __shared__ __align__(16) bf16 lsV[2][64 * 64];
    __shared__ __align__(16) bf16 lsP[4][16 * 64];

    const int tid = threadIdx.x;
    const int lane = tid & 63;
    const int w = tid >> 6;
    const int l15 = lane & 15, l4 = lane >> 4;
    const int bh = blockIdx.y;
    const int b = bh >> 4, h = bh & 15;
    const int q0 = blockIdx.x * 64;

    const bf16* qp = Q + ((long)bh * 1024 + q0 + w * 16 + l15) * 64;
    bf16x8 qa[2];
    qa[0] = *(const bf16x8*)(qp + 8 * l4);
    qa[1] = *(const bf16x8*)(qp + 32 + 8 * l4);

    const bf16* kbase = Kv + (long)bh * 1024 * 64;
    const bf16* vbase = Vt + (long)bh * 64 * 1024;

    float lsum[4] = {0.f, 0.f, 0.f, 0.f};
    f32x4 oacc[4] = {};

    stage_swz<64>(kbase, 64, lsK[0], tid);
    stage_swz<64>(vbase, 1024, lsV[0], tid);
    __syncthreads();

    for (int t = 0; t < 16; ++t) {
        const int cur = t & 1;
        if (t < 15) {
            int kv0 = (t + 1) * 64;
            stage_swz<64>(kbase + (long)kv0 * 64, 64, lsK[cur ^ 1], tid);
            stage_swz<64>(vbase + kv0, 1024, lsV[cur ^ 1], tid);
        }

        f32x4 s[4] = {};
#pragma unroll
        for (int kk = 0; kk < 2; ++kk) {
            int c8 = kk * 4 + l4;
#pragma unroll
            for (int nt = 0; nt < 4; ++nt) {
                bf16x8 kb = *(const bf16x8*)(&lsK[cur][LDS_SWZ8(nt * 16 + l15, c8)]);
                s[nt] = __builtin_amdgcn_mfma_f32_16x16x32_bf16(qa[kk], kb, s[nt], 0, 0, 0);
            }
        }

#pragma unroll
        for (int i = 0; i < 4; ++i) {
            int prow = l4 * 4 + i;
#pragma unroll
            for (int nt = 0; nt < 4; ++nt) {
                float p = __expf(s[nt][i]);
                lsum[i] += p;
                lsP[w][swz_idx(prow, nt * 16 + l15)] = (bf16)p;
            }
        }
        __builtin_amdgcn_sched_barrier(0);
        asm volatile("s_waitcnt lgkmcnt(0)" ::: "memory");
        __builtin_amdgcn_sched_barrier(0);

#pragma unroll
        for (int kk = 0; kk < 2; ++kk) {
            int c8 = kk * 4 + l4;
            bf16x8 pa = *(const bf16x8*)(&lsP[w][LDS_SWZ8(l15, c8)]);
#pragma unroll
            for (int nt = 0; nt < 4; ++nt) {
                bf16x8 vb = *(const bf16x8*)(&lsV[cur][LDS_SWZ8(nt * 16 + l15, c8)]);
                oacc[nt] = __builtin_amdgcn_mfma_f32_16x16x32_bf16(pa, vb, oacc[nt], 0, 0, 0);
            }
        }
        __syncthreads();
    }

#pragma unroll
    for (int i = 0; i < 4; ++i) {
#pragma unroll
        for (int off = 1; off < 16; off <<= 1)
            lsum[i] += __shfl_xor(lsum[i], off);
    }

#pragma unroll
    for (int i = 0; i < 4; ++i) {
        float rinv = 1.0f / lsum[i];
        int row = q0 + w * 16 + l4 * 4 + i;
#pragma unroll
        for (int nt = 0; nt < 4; ++nt) {
            int d = nt * 16 + l15;
            Y[((long)b * 1024 + row) * 1024 + h * 64 + d] = (bf16)(oacc[nt][i] * rinv);
        }
    }
}

// ---------------------------------------------------------------------------
// LayerNorm kernels
// ---------------------------------------------------------------------------
__device__ __forceinline__ float block_reduce_sum(float v, float* sm) {
#pragma unroll
    for (int off = 1; off < 64; off <<= 1) v += __shfl_xor(v, off);
    int w = threadIdx.x >> 6;
    if ((threadIdx.x & 63) == 0) sm[w] = v;
    __syncthreads();
    v = sm[0] + sm[1] + sm[2] + sm[3];
    __syncthreads();
    return v;
}

__global__ __launch_bounds__(256)
void res_ln(float* __restrict__ Yf, bf16* __restrict__ Yb,
            const float* __restrict__ g, const float* __restrict__ beta) {
    __shared__ float sm[4];
    const long row = blockIdx.x;
    float* p = Yf + row * 1024;
    const int t = threadIdx.x;
    float4 x = *(const float4*)(p + t * 4);
    float s = x.x + x.y + x.z + x.w;
    s = block_reduce_sum(s, sm);
    float mean = s * (1.0f / 1024.0f);
    float d0 = x.x - mean, d1 = x.y - mean, d2 = x.z - mean, d3 = x.w - mean;
    float sq = d0 * d0 + d1 * d1 + d2 * d2 + d3 * d3;
    sq = block_reduce_sum(sq, sm);
    float rs = rsqrtf(sq * (1.0f / 1024.0f) + 1e-6f);
    float4 gg = *(const float4*)(g + t * 4);
    float4 bb = *(const float4*)(beta + t * 4);
    float o0 = x.x + d0 * rs * gg.x + bb.x;
    float o1 = x.y + d1 * rs * gg.y + bb.y;
    float o2 = x.z + d2 * rs * gg.z + bb.z;
    float o3 = x.w + d3 * rs * gg.w + bb.w;
    *(float4*)(p + t * 4) = make_float4(o0, o1, o2, o3);
    short4 pk;
    pk.x = (short)__builtin_bit_cast(unsigned short, (bf16)o0);
    pk.y = (short)__builtin_bit_cast(unsigned short, (bf16)o1);
    pk.z = (short)__builtin_bit_cast(unsigned short, (bf16)o2);
    pk.w = (short)__builtin_bit_cast(unsigned short, (bf16)o3);
    *(short4*)(Yb + row * 1024 + t * 4) = pk;
}

__global__ __launch_bounds__(256)
void final_ln(float* __restrict__ Hf, const float* __restrict__ Yres,
              const float* __restrict__ g, const float* __restrict__ beta) {
    __shared__ float sm[4];
    const long row = blockIdx.x;
    float* p = Hf + row * 1024;
    const float* yr = Yres + row * 1024;
    const int t = threadIdx.x;
    float4 x = *(const float4*)(p + t * 4);
    float s = x.x + x.y + x.z + x.w;
    s = block_reduce_sum(s, sm);
    float mean = s * (1.0f / 1024.0f);
    float d0 = x.x - mean, d1 = x.y - mean, d2 = x.z - mean, d3 = x.w - mean;
    float sq = d0 * d0 + d1 * d1 + d2 * d2 + d3 * d3;
    sq = block_reduce_sum(sq, sm);
    float rs = rsqrtf(sq * (1.0f / 1024.0f) + 1e-6f);
    float4 gg = *(const float4*)(g + t * 4);
    float4 bb = *(const float4*)(beta + t * 4);
    float4 y = *(const float4*)(yr + t * 4);
    float4 o;
    o.x = y.x + d0 * rs * gg.x + bb.x;
    o.y = y.y + d1 * rs * gg.y + bb.y;
    o.z = y.z + d2 * rs * gg.z + bb.z;
    o.w = y.w + d3 * rs * gg.w + bb.w;
    *(float4*)(p + t * 4) = o;
}

// ---------------------------------------------------------------------------
extern "C" void kernel_launch(void* const* d_in, const int* in_sizes, int n_in,
                              void* d_out, int out_size, void* d_ws, size_t ws_size,
                              hipStream_t stream) {
    const float* x      = (const float*)d_in[0];
    const float* qkv_w  = (const float*)d_in[1];
    const float* qkv_b  = (const float*)d_in[2];
    const float* proj_w = (const float*)d_in[3];
    const float* proj_b = (const float*)d_in[4];
    const float* n1_g   = (const float*)d_in[5];
    const float* n1_b   = (const float*)d_in[6];
    const float* fc1_w  = (const float*)d_in[7];
    const float* fc1_b  = (const float*)d_in[8];
    const float* fc2_w  = (const float*)d_in[9];
    const float* fc2_b  = (const float*)d_in[10];
    const float* n2_g   = (const float*)d_in[11];
    const float* n2_b   = (const float*)d_in[12];

    char* ws = (char*)d_ws;
    const long MB = 1l << 20;
    bf16*  qkvT  = (bf16*)(ws + 0 * MB);
    bf16*  projT = (bf16*)(ws + 6 * MB);
    bf16*  fc1T  = (bf16*)(ws + 8 * MB);
    bf16*  fc2T  = (bf16*)(ws + 16 * MB);
    bf16*  xbf   = (bf16*)(ws + 24 * MB);
    bf16*  yattn = (bf16*)(ws + 24 * MB);
    bf16*  qb    = (bf16*)(ws + 40 * MB);
    bf16*  kb    = (bf16*)(ws + 56 * MB);
    bf16*  vtb   = (bf16*)(ws + 72 * MB);
    float* yproj = (float*)(ws + 40 * MB);
    bf16*  yresb = (bf16*)(ws + 72 * MB);
    bf16*  h1    = (bf16*)(ws + 88 * MB);
    float* outf  = (float*)d_out;

    dim3 tb(32, 8);
    transpose_cvt<<<dim3(3072 / 32, 1024 / 32), tb, 0, stream>>>(qkv_w, qkvT, 1024, 3072);
    transpose_cvt<<<dim3(1024 / 32, 1024 / 32), tb, 0, stream>>>(proj_w, projT, 1024, 1024);
    transpose_cvt<<<dim3(4096 / 32, 1024 / 32), tb, 0, stream>>>(fc1_w, fc1T, 1024, 4096);
    transpose_cvt<<<dim3(1024 / 32, 4096 / 32), tb, 0, stream>>>(fc2_w, fc2T, 4096, 1024);
    cvt_bf16_kernel<<<8192, 256, 0, stream>>>(x, xbf, 8388608);

    // qkv: [8192,1024] x [1024,3072]
    gemm_tb<0, 1024><<<dim3(3072 / 128, 8192 / 256), 512, 0, stream>>>(
        xbf, qkvT, qkv_b, nullptr, qb, kb, vtb, 8192, 3072);
    attn_flash<<<dim3(1024 / 64, 128), 256, 0, stream>>>(qb, kb, vtb, yattn);
    // proj
    gemm_tb<1, 1024><<<dim3(1024 / 128, 8192 / 256), 512, 0, stream>>>(
        yattn, projT, proj_b, yproj, nullptr, nullptr, nullptr, 8192, 1024);
    res_ln<<<8192, 256, 0, stream>>>(yproj, yresb, n1_g, n1_b);
    // fc1 + GELU
    gemm_tb<2, 1024><<<dim3(4096 / 128, 8192 / 256), 512, 0, stream>>>(
        yresb, fc1T, fc1_b, nullptr, h1, nullptr, nullptr, 8192, 4096);
    // fc2 -> d_out
    gemm_tb<3, 4096><<<dim3(1024 / 128, 8192 / 256), 512, 0, stream>>>(
        h1, fc2T, fc2_b, outf, nullptr, nullptr, nullptr, 8192, 1024);
    final_ln<<<8192, 256, 0, stream>>>(outf, yproj, n2_g, n2_b);
}

// Round 7
// 370.806 us; speedup vs baseline: 1.2764x; 1.2764x over previous
//
#include <hip/hip_runtime.h>
#include <hip/hip_bf16.h>
#include <math.h>

typedef __bf16 bf16;
typedef __bf16 bf16x8 __attribute__((ext_vector_type(8)));
typedef float f32x4 __attribute__((ext_vector_type(4)));

// XOR-swizzled element index into a row-major [R][64] bf16 LDS tile.
__device__ __forceinline__ int swz_idx(int row, int col) {
    return ((row) << 6) + (((((col) >> 3) ^ ((row) & 7)) << 3) | ((col) & 7));
}
#define LDS_SWZ8(row, c8) ((((row)) << 6) + ((((c8) ^ ((row) & 7))) << 3))

// global -> LDS direct copy, 16B per lane
__device__ __forceinline__ void gload_lds16(const bf16* g, bf16* l) {
    __builtin_amdgcn_global_load_lds(
        (const __attribute__((address_space(1))) void*)g,
        (__attribute__((address_space(3))) void*)l,
        16, 0, 0);
}

// Stage ROWS x 64 bf16 tile into LDS: linear LDS dest, pre-swizzled global
// source (rule #21: source permutation == read permutation).
template <int ROWS>
__device__ __forceinline__ void stage_swz(const bf16* __restrict__ src, long rstride,
                                          bf16* lds, int tid) {
#pragma unroll
    for (int pass = 0; pass < ROWS / 32; ++pass) {
        int e = pass * 2048 + tid * 8;
        int r = e >> 6;
        int c8 = (e >> 3) & 7;
        int sc8 = c8 ^ (r & 7);
        gload_lds16(src + (long)r * rstride + sc8 * 8, lds + e);
    }
}

// ---------------------------------------------------------------------------
// Weight transpose + fp32->bf16:  src [R][C] fp32  ->  dst [C][R] bf16
// ---------------------------------------------------------------------------
__global__ void transpose_cvt(const float* __restrict__ src, bf16* __restrict__ dst,
                              int R, int C) {
    __shared__ float tile[32][33];
    int bx = blockIdx.x * 32;
    int by = blockIdx.y * 32;
    int tx = threadIdx.x, ty = threadIdx.y;
#pragma unroll
    for (int j = 0; j < 32; j += 8)
        tile[ty + j][tx] = src[(long)(by + ty + j) * C + bx + tx];
    __syncthreads();
#pragma unroll
    for (int j = 0; j < 32; j += 8)
        dst[(long)(bx + ty + j) * R + by + tx] = (bf16)tile[tx][ty + j];
}

__global__ void cvt_bf16_kernel(const float* __restrict__ src, bf16* __restrict__ dst,
                                long n) {
    long i = ((long)blockIdx.x * blockDim.x + threadIdx.x) * 4;
    if (i < n) {
        float4 v = *(const float4*)(src + i);
        short4 pk;
        pk.x = (short)__builtin_bit_cast(unsigned short, (bf16)v.x);
        pk.y = (short)__builtin_bit_cast(unsigned short, (bf16)v.y);
        pk.z = (short)__builtin_bit_cast(unsigned short, (bf16)v.z);
        pk.w = (short)__builtin_bit_cast(unsigned short, (bf16)v.w);
        *(short4*)(dst + i) = pk;
    }
}

// ---------------------------------------------------------------------------
// GEMM (r2-proven structure): C[M][N] = A[M][K]*Bt[N][K]^T + bias.
// 128x128 tile, BK=64, 256 thr (4 waves 2x2, 64x64/wave), 32 KiB LDS ->
// ~5 blocks/CU co-resident (inter-block overlap hides barrier drain, m114).
// + XCD-aware bijective block swizzle (T1): consecutive blocks in one XCD
// chunk share the A row-panel -> L2-local re-reads instead of HBM.
// MODE 0: qkv split epilogue (q*SCALE*log2e, k, v-transposed), bf16 out
// MODE 1: fp32 out (proj);  MODE 2: GELU->bf16 (fc1);  MODE 3: fp32 (fc2)
// ---------------------------------------------------------------------------
template <int MODE>
__global__ __launch_bounds__(256, 2)
void gemm_bt(const bf16* __restrict__ A, const bf16* __restrict__ Bt,
             const float* __restrict__ bias,
             float* __restrict__ Cf, bf16* __restrict__ Cb0,
             bf16* __restrict__ Cb1, bf16* __restrict__ Cb2,
             int M, int N, int K) {
    __shared__ __align__(16) bf16 lsA[128 * 64];
    __shared__ __align__(16) bf16 lsB[128 * 64];

    // XCD-aware bijective swizzle (grid % 8 == 0 for all our launches)
    const int nwg = gridDim.x * gridDim.y;
    const int lin = blockIdx.y * gridDim.x + blockIdx.x;
    const int swz = (lin & 7) * (nwg >> 3) + (lin >> 3);
    const int bx = swz % gridDim.x, by = swz / gridDim.x;

    const int tid = threadIdx.x;
    const int lane = tid & 63;
    const int w = tid >> 6;
    const int wm = w >> 1, wn = w & 1;
    const int l15 = lane & 15, l4 = lane >> 4;
    const int row0 = by * 128;
    const int col0 = bx * 128;

    f32x4 acc[4][4] = {};

    for (int k0 = 0; k0 < K; k0 += 64) {
        stage_swz<128>(A + (long)row0 * K + k0, K, lsA, tid);
        stage_swz<128>(Bt + (long)col0 * K + k0, K, lsB, tid);
        __syncthreads();
#pragma unroll
        for (int kk = 0; kk < 2; ++kk) {
            int c8 = kk * 4 + l4;
            bf16x8 af[4], bfr[4];
#pragma unroll
            for (int mt = 0; mt < 4; ++mt)
                af[mt] = *(const bf16x8*)(&lsA[LDS_SWZ8(wm * 64 + mt * 16 + l15, c8)]);
#pragma unroll
            for (int nt = 0; nt < 4; ++nt)
                bfr[nt] = *(const bf16x8*)(&lsB[LDS_SWZ8(wn * 64 + nt * 16 + l15, c8)]);
#pragma unroll
            for (int mt = 0; mt < 4; ++mt)
#pragma unroll
                for (int nt = 0; nt < 4; ++nt)
                    acc[mt][nt] = __builtin_amdgcn_mfma_f32_16x16x32_bf16(
                        af[mt], bfr[nt], acc[mt][nt], 0, 0, 0);
        }
        __syncthreads();
    }

    // ---- epilogue ----
#pragma unroll
    for (int mt = 0; mt < 4; ++mt) {
#pragma unroll
        for (int nt = 0; nt < 4; ++nt) {
            int colb = col0 + wn * 64 + nt * 16 + l15;
            float bv = bias[colb];
#pragma unroll
            for (int i = 0; i < 4; ++i) {
                int row = row0 + wm * 64 + mt * 16 + l4 * 4 + i;
                int col = colb;
                float v = acc[mt][nt][i] + bv;
                if (MODE == 0) {
                    int b = row >> 10, nn = row & 1023;
                    int s = col >> 10, rem = col & 1023;
                    int h = rem >> 6, d = rem & 63;
                    long bh = (long)b * 16 + h;
                    // q pre-scaled by SCALE*log2(e) so attn uses exp2 directly
                    if (s == 0)      Cb0[(bh * 1024 + nn) * 64 + d] = (bf16)(v * 0.1803368881f);
                    else if (s == 1) Cb1[(bh * 1024 + nn) * 64 + d] = (bf16)v;
                    else             Cb2[(bh * 64 + d) * 1024 + nn] = (bf16)v;
                } else if (MODE == 1) {
                    Cf[(long)row * N + col] = v;
                } else if (MODE == 2) {
                    float g = 0.5f * v * (1.0f + erff(v * 0.70710678118f));
                    Cb0[(long)row * N + col] = (bf16)g;
                } else {
                    Cf[(long)row * N + col] = v;
                }
            }
        }
    }
}

// ---------------------------------------------------------------------------
// Flash attention, no-max softmax (bounded S), dbuf K/V via global_load_lds.
// Q pre-scaled by SCALE*log2e -> P = exp2(S) (v_exp_f32 is natively exp2).
// ---------------------------------------------------------------------------
__global__ __launch_bounds__(256, 2)
void attn_flash(const bf16* __restrict__ Q, const bf16* __restrict__ Kv,
                const bf16* __restrict__ Vt, bf16* __restrict__ Y) {
    __shared__ __align__(16) bf16 lsK[2][64 * 64];
    __shared__ __align__(16) bf16 lsV[2][64 * 64];
    __shared__ __align__(16) bf16 lsP[4][16 * 64];

    const int tid = threadIdx.x;
    const int lane = tid & 63;
    const int w = tid >> 6;
    const int l15 = lane & 15, l4 = lane >> 4;
    const int bh = blockIdx.y;
    const int b = bh >> 4, h = bh & 15;
    const int q0 = blockIdx.x * 64;

    const bf16* qp = Q + ((long)bh * 1024 + q0 + w * 16 + l15) * 64;
    bf16x8 qa[2];
    qa[0] = *(const bf16x8*)(qp + 8 * l4);
    qa[1] = *(const bf16x8*)(qp + 32 + 8 * l4);

    const bf16* kbase = Kv + (long)bh * 1024 * 64;
    const bf16* vbase = Vt + (long)bh * 64 * 1024;

    float lsum[4] = {0.f, 0.f, 0.f, 0.f};
    f32x4 oacc[4] = {};

    stage_swz<64>(kbase, 64, lsK[0], tid);
    stage_swz<64>(vbase, 1024, lsV[0], tid);
    __syncthreads();

    for (int t = 0; t < 16; ++t) {
        const int cur = t & 1;
        if (t < 15) {
            int kv0 = (t + 1) * 64;
            stage_swz<64>(kbase + (long)kv0 * 64, 64, lsK[cur ^ 1], tid);
            stage_swz<64>(vbase + kv0, 1024, lsV[cur ^ 1], tid);
        }

        f32x4 s[4] = {};
        __builtin_amdgcn_s_setprio(1);
#pragma unroll
        for (int kk = 0; kk < 2; ++kk) {
            int c8 = kk * 4 + l4;
#pragma unroll
            for (int nt = 0; nt < 4; ++nt) {
                bf16x8 kb = *(const bf16x8*)(&lsK[cur][LDS_SWZ8(nt * 16 + l15, c8)]);
                s[nt] = __builtin_amdgcn_mfma_f32_16x16x32_bf16(qa[kk], kb, s[nt], 0, 0, 0);
            }
        }
        __builtin_amdgcn_s_setprio(0);

#pragma unroll
        for (int i = 0; i < 4; ++i) {
            int prow = l4 * 4 + i;
#pragma unroll
            for (int nt = 0; nt < 4; ++nt) {
                float p = exp2f(s[nt][i]);   // exact e^S (log2e folded into Q)
                lsum[i] += p;
                lsP[w][swz_idx(prow, nt * 16 + l15)] = (bf16)p;
            }
        }
        __builtin_amdgcn_sched_barrier(0);
        asm volatile("s_waitcnt lgkmcnt(0)" ::: "memory");
        __builtin_amdgcn_sched_barrier(0);

        __builtin_amdgcn_s_setprio(1);
#pragma unroll
        for (int kk = 0; kk < 2; ++kk) {
            int c8 = kk * 4 + l4;
            bf16x8 pa = *(const bf16x8*)(&lsP[w][LDS_SWZ8(l15, c8)]);
#pragma unroll
            for (int nt = 0; nt < 4; ++nt) {
                bf16x8 vb = *(const bf16x8*)(&lsV[cur][LDS_SWZ8(nt * 16 + l15, c8)]);
                oacc[nt] = __builtin_amdgcn_mfma_f32_16x16x32_bf16(pa, vb, oacc[nt], 0, 0, 0);
            }
        }
        __builtin_amdgcn_s_setprio(0);
        __syncthreads();
    }

#pragma unroll
    for (int i = 0; i < 4; ++i) {
#pragma unroll
        for (int off = 1; off < 16; off <<= 1)
            lsum[i] += __shfl_xor(lsum[i], off);
    }

#pragma unroll
    for (int i = 0; i < 4; ++i) {
        float rinv = 1.0f / lsum[i];
        int row = q0 + w * 16 + l4 * 4 + i;
#pragma unroll
        for (int nt = 0; nt < 4; ++nt) {
            int d = nt * 16 + l15;
            Y[((long)b * 1024 + row) * 1024 + h * 64 + d] = (bf16)(oacc[nt][i] * rinv);
        }
    }
}

// ---------------------------------------------------------------------------
// LayerNorm kernels
// ---------------------------------------------------------------------------
__device__ __forceinline__ float block_reduce_sum(float v, float* sm) {
#pragma unroll
    for (int off = 1; off < 64; off <<= 1) v += __shfl_xor(v, off);
    int w = threadIdx.x >> 6;
    if ((threadIdx.x & 63) == 0) sm[w] = v;
    __syncthreads();
    v = sm[0] + sm[1] + sm[2] + sm[3];
    __syncthreads();
    return v;
}

__global__ __launch_bounds__(256)
void res_ln(float* __restrict__ Yf, bf16* __restrict__ Yb,
            const float* __restrict__ g, const float* __restrict__ beta) {
    __shared__ float sm[4];
    const long row = blockIdx.x;
    float* p = Yf + row * 1024;
    const int t = threadIdx.x;
    float4 x = *(const float4*)(p + t * 4);
    float s = x.x + x.y + x.z + x.w;
    s = block_reduce_sum(s, sm);
    float mean = s * (1.0f / 1024.0f);
    float d0 = x.x - mean, d1 = x.y - mean, d2 = x.z - mean, d3 = x.w - mean;
    float sq = d0 * d0 + d1 * d1 + d2 * d2 + d3 * d3;
    sq = block_reduce_sum(sq, sm);
    float rs = rsqrtf(sq * (1.0f / 1024.0f) + 1e-6f);
    float4 gg = *(const float4*)(g + t * 4);
    float4 bb = *(const float4*)(beta + t * 4);
    float o0 = x.x + d0 * rs * gg.x + bb.x;
    float o1 = x.y + d1 * rs * gg.y + bb.y;
    float o2 = x.z + d2 * rs * gg.z + bb.z;
    float o3 = x.w + d3 * rs * gg.w + bb.w;
    *(float4*)(p + t * 4) = make_float4(o0, o1, o2, o3);
    short4 pk;
    pk.x = (short)__builtin_bit_cast(unsigned short, (bf16)o0);
    pk.y = (short)__builtin_bit_cast(unsigned short, (bf16)o1);
    pk.z = (short)__builtin_bit_cast(unsigned short, (bf16)o2);
    pk.w = (short)__builtin_bit_cast(unsigned short, (bf16)o3);
    *(short4*)(Yb + row * 1024 + t * 4) = pk;
}

__global__ __launch_bounds__(256)
void final_ln(float* __restrict__ Hf, const float* __restrict__ Yres,
              const float* __restrict__ g, const float* __restrict__ beta) {
    __shared__ float sm[4];
    const long row = blockIdx.x;
    float* p = Hf + row * 1024;
    const float* yr = Yres + row * 1024;
    const int t = threadIdx.x;
    float4 x = *(const float4*)(p + t * 4);
    float s = x.x + x.y + x.z + x.w;
    s = block_reduce_sum(s, sm);
    float mean = s * (1.0f / 1024.0f);
    float d0 = x.x - mean, d1 = x.y - mean, d2 = x.z - mean, d3 = x.w - mean;
    float sq = d0 * d0 + d1 * d1 + d2 * d2 + d3 * d3;
    sq = block_reduce_sum(sq, sm);
    float rs = rsqrtf(sq * (1.0f / 1024.0f) + 1e-6f);
    float4 gg = *(const float4*)(g + t * 4);
    float4 bb = *(const float4*)(beta + t * 4);
    float4 y = *(const float4*)(yr + t * 4);
    float4 o;
    o.x = y.x + d0 * rs * gg.x + bb.x;
    o.y = y.y + d1 * rs * gg.y + bb.y;
    o.z = y.z + d2 * rs * gg.z + bb.z;
    o.w = y.w + d3 * rs * gg.w + bb.w;
    *(float4*)(p + t * 4) = o;
}

// ---------------------------------------------------------------------------
extern "C" void kernel_launch(void* const* d_in, const int* in_sizes, int n_in,
                              void* d_out, int out_size, void* d_ws, size_t ws_size,
                              hipStream_t stream) {
    const float* x      = (const float*)d_in[0];
    const float* qkv_w  = (const float*)d_in[1];
    const float* qkv_b  = (const float*)d_in[2];
    const float* proj_w = (const float*)d_in[3];
    const float* proj_b = (const float*)d_in[4];
    const float* n1_g   = (const float*)d_in[5];
    const float* n1_b   = (const float*)d_in[6];
    const float* fc1_w  = (const float*)d_in[7];
    const float* fc1_b  = (const float*)d_in[8];
    const float* fc2_w  = (const float*)d_in[9];
    const float* fc2_b  = (const float*)d_in[10];
    const float* n2_g   = (const float*)d_in[11];
    const float* n2_b   = (const float*)d_in[12];

    char* ws = (char*)d_ws;
    const long MB = 1l << 20;
    bf16*  qkvT  = (bf16*)(ws + 0 * MB);
    bf16*  projT = (bf16*)(ws + 6 * MB);
    bf16*  fc1T  = (bf16*)(ws + 8 * MB);
    bf16*  fc2T  = (bf16*)(ws + 16 * MB);
    bf16*  xbf   = (bf16*)(ws + 24 * MB);
    bf16*  yattn = (bf16*)(ws + 24 * MB);
    bf16*  qb    = (bf16*)(ws + 40 * MB);
    bf16*  kb    = (bf16*)(ws + 56 * MB);
    bf16*  vtb   = (bf16*)(ws + 72 * MB);
    float* yproj = (float*)(ws + 40 * MB);
    bf16*  yresb = (bf16*)(ws + 72 * MB);
    bf16*  h1    = (bf16*)(ws + 88 * MB);
    float* outf  = (float*)d_out;

    dim3 tb(32, 8);
    transpose_cvt<<<dim3(3072 / 32, 1024 / 32), tb, 0, stream>>>(qkv_w, qkvT, 1024, 3072);
    transpose_cvt<<<dim3(1024 / 32, 1024 / 32), tb, 0, stream>>>(proj_w, projT, 1024, 1024);
    transpose_cvt<<<dim3(4096 / 32, 1024 / 32), tb, 0, stream>>>(fc1_w, fc1T, 1024, 4096);
    transpose_cvt<<<dim3(1024 / 32, 4096 / 32), tb, 0, stream>>>(fc2_w, fc2T, 4096, 1024);
    cvt_bf16_kernel<<<8192, 256, 0, stream>>>(x, xbf, 8388608);

    // qkv: [8192,1024] x [1024,3072] -> q,k,vT (bf16)
    gemm_bt<0><<<dim3(3072 / 128, 8192 / 128), 256, 0, stream>>>(
        xbf, qkvT, qkv_b, nullptr, qb, kb, vtb, 8192, 3072, 1024);
    attn_flash<<<dim3(1024 / 64, 128), 256, 0, stream>>>(qb, kb, vtb, yattn);
    // proj
    gemm_bt<1><<<dim3(1024 / 128, 8192 / 128), 256, 0, stream>>>(
        yattn, projT, proj_b, yproj, nullptr, nullptr, nullptr, 8192, 1024, 1024);
    res_ln<<<8192, 256, 0, stream>>>(yproj, yresb, n1_g, n1_b);
    // fc1 + GELU
    gemm_bt<2><<<dim3(4096 / 128, 8192 / 128), 256, 0, stream>>>(
        yresb, fc1T, fc1_b, nullptr, h1, nullptr, nullptr, 8192, 4096, 1024);
    // fc2 -> d_out
    gemm_bt<3><<<dim3(1024 / 128, 8192 / 128), 256, 0, stream>>>(
        h1, fc2T, fc2_b, outf, nullptr, nullptr, nullptr, 8192, 1024, 4096);
    final_ln<<<8192, 256, 0, stream>>>(outf, yproj, n2_g, n2_b);
}